// Round 1
// baseline (535.545 us; speedup 1.0000x reference)
//
#include <hip/hip_runtime.h>
#include <math.h>

// ---------------- CSR build ----------------

__global__ __launch_bounds__(256) void k_count(const int* __restrict__ dst,
                                               int* __restrict__ cnt, int e) {
    int i = blockIdx.x * 256 + threadIdx.x;
    if (i < e) atomicAdd(&cnt[dst[i]], 1);
}

// block handles 1024 elements (4/thread); writes exclusive scan within block + block total
__global__ __launch_bounds__(256) void k_scan_local(const int* __restrict__ cnt,
                                                    int* __restrict__ row_start,
                                                    int* __restrict__ partials, int n) {
    __shared__ int sdata[256];
    int tid = threadIdx.x;
    int base = blockIdx.x * 1024 + tid * 4;
    int v0 = (base + 0 < n) ? cnt[base + 0] : 0;
    int v1 = (base + 1 < n) ? cnt[base + 1] : 0;
    int v2 = (base + 2 < n) ? cnt[base + 2] : 0;
    int v3 = (base + 3 < n) ? cnt[base + 3] : 0;
    int s = v0 + v1 + v2 + v3;
    sdata[tid] = s;
    __syncthreads();
    for (int off = 1; off < 256; off <<= 1) {
        int y = (tid >= off) ? sdata[tid - off] : 0;
        __syncthreads();
        sdata[tid] += y;
        __syncthreads();
    }
    int run = sdata[tid] - s;  // exclusive prefix within block
    if (base + 0 < n) row_start[base + 0] = run;
    run += v0;
    if (base + 1 < n) row_start[base + 1] = run;
    run += v1;
    if (base + 2 < n) row_start[base + 2] = run;
    run += v2;
    if (base + 3 < n) row_start[base + 3] = run;
    if (tid == 255) partials[blockIdx.x] = sdata[255];
}

// exclusive scan of up to 256 partials in-place (single block)
__global__ __launch_bounds__(256) void k_scan_partials(int* partials, int nb) {
    __shared__ int sdata[256];
    int tid = threadIdx.x;
    int v = (tid < nb) ? partials[tid] : 0;
    sdata[tid] = v;
    __syncthreads();
    for (int off = 1; off < 256; off <<= 1) {
        int y = (tid >= off) ? sdata[tid - off] : 0;
        __syncthreads();
        sdata[tid] += y;
        __syncthreads();
    }
    if (tid < nb) partials[tid] = sdata[tid] - v;
}

__global__ __launch_bounds__(256) void k_scan_add(int* __restrict__ row_start,
                                                  const int* __restrict__ partials,
                                                  int n, int total) {
    int i = blockIdx.x * 256 + threadIdx.x;
    if (i < n) row_start[i] += partials[i >> 10];
    if (i == 0) row_start[n] = total;
}

__global__ __launch_bounds__(256) void k_scatter(const int* __restrict__ src,
                                                 const int* __restrict__ dst,
                                                 const int* __restrict__ row_start,
                                                 int* __restrict__ fill,
                                                 int* __restrict__ csr_src, int e) {
    int i = blockIdx.x * 256 + threadIdx.x;
    if (i < e) {
        int d = dst[i];
        int pos = row_start[d] + atomicAdd(&fill[d], 1);
        csr_src[pos] = src[i];
    }
}

// ---------------- Layer 1 GEMM: [N,128] @ [128,128] + fused el/er ----------------
// BM=64 nodes, full K=128, thread = 4 nodes x 8 cols. sX padded to 132 (bank-conflict-free).

__global__ __launch_bounds__(256) void k_gemm1(const float* __restrict__ X,
                                               const float* __restrict__ W,
                                               const float* __restrict__ attn_l,
                                               const float* __restrict__ attn_r,
                                               float* __restrict__ feat,
                                               float* __restrict__ el,
                                               float* __restrict__ er, int n) {
    __shared__ float sW[128 * 128];
    __shared__ float sX[64 * 132];
    int t = threadIdx.x;
    {
        const float4* Wv = (const float4*)W;
        float4* sWv = (float4*)sW;
#pragma unroll
        for (int i = 0; i < 16; ++i) sWv[t + i * 256] = Wv[t + i * 256];
    }
    int node0 = blockIdx.x * 64;
    {
        const float4* Xv = (const float4*)X;
        for (int i = t; i < 64 * 32; i += 256) {
            int r = i >> 5, q = i & 31;
            int node = node0 + r;
            float4 val = make_float4(0.f, 0.f, 0.f, 0.f);
            if (node < n) val = Xv[(size_t)node * 32 + q];
            *(float4*)(sX + r * 132 + q * 4) = val;
        }
    }
    __syncthreads();
    int tr = t >> 4, tc = t & 15;  // tr 0..15, tc 0..15 -> cols 8*tc..8*tc+7
    float acc[4][8] = {};
    for (int k = 0; k < 128; ++k) {
        float4 w0 = *(const float4*)(sW + k * 128 + tc * 8);
        float4 w1 = *(const float4*)(sW + k * 128 + tc * 8 + 4);
#pragma unroll
        for (int i = 0; i < 4; ++i) {
            float xk = sX[(tr + 16 * i) * 132 + k];
            acc[i][0] += xk * w0.x; acc[i][1] += xk * w0.y;
            acc[i][2] += xk * w0.z; acc[i][3] += xk * w0.w;
            acc[i][4] += xk * w1.x; acc[i][5] += xk * w1.y;
            acc[i][6] += xk * w1.z; acc[i][7] += xk * w1.w;
        }
    }
    int h = tc >> 2;              // head 0..3
    int dbase = (tc & 3) * 8;     // dim-in-head base
    float al[8], ar[8];
#pragma unroll
    for (int j = 0; j < 8; ++j) {
        al[j] = attn_l[h * 32 + dbase + j];
        ar[j] = attn_r[h * 32 + dbase + j];
    }
#pragma unroll
    for (int i = 0; i < 4; ++i) {
        int node = node0 + tr + 16 * i;
        float pl = 0.f, pr = 0.f;
#pragma unroll
        for (int j = 0; j < 8; ++j) { pl += acc[i][j] * al[j]; pr += acc[i][j] * ar[j]; }
        pl += __shfl_xor(pl, 1); pl += __shfl_xor(pl, 2);
        pr += __shfl_xor(pr, 1); pr += __shfl_xor(pr, 2);
        if (node < n) {
            float4 f0 = make_float4(acc[i][0], acc[i][1], acc[i][2], acc[i][3]);
            float4 f1 = make_float4(acc[i][4], acc[i][5], acc[i][6], acc[i][7]);
            *(float4*)(feat + (size_t)node * 128 + tc * 8) = f0;
            *(float4*)(feat + (size_t)node * 128 + tc * 8 + 4) = f1;
            if ((tc & 3) == 0) { el[node * 4 + h] = pl; er[node * 4 + h] = pr; }
        }
    }
}

// ---------------- Layer 2 GEMM: [N,128] @ [128,64] + fused el/er (H=1) ----------------

__global__ __launch_bounds__(256) void k_gemm2(const float* __restrict__ X,
                                               const float* __restrict__ W,
                                               const float* __restrict__ attn_l,
                                               const float* __restrict__ attn_r,
                                               float* __restrict__ feat,
                                               float* __restrict__ el,
                                               float* __restrict__ er, int n) {
    __shared__ float sW[128 * 64];
    __shared__ float sX[64 * 132];
    int t = threadIdx.x;
    {
        const float4* Wv = (const float4*)W;
        float4* sWv = (float4*)sW;
#pragma unroll
        for (int i = 0; i < 8; ++i) sWv[t + i * 256] = Wv[t + i * 256];
    }
    int node0 = blockIdx.x * 64;
    {
        const float4* Xv = (const float4*)X;
        for (int i = t; i < 64 * 32; i += 256) {
            int r = i >> 5, q = i & 31;
            int node = node0 + r;
            float4 val = make_float4(0.f, 0.f, 0.f, 0.f);
            if (node < n) val = Xv[(size_t)node * 32 + q];
            *(float4*)(sX + r * 132 + q * 4) = val;
        }
    }
    __syncthreads();
    int tr = t >> 3, tc = t & 7;  // tr 0..31, tc 0..7 -> cols 8*tc..8*tc+7
    float acc[2][8] = {};
    for (int k = 0; k < 128; ++k) {
        float4 w0 = *(const float4*)(sW + k * 64 + tc * 8);
        float4 w1 = *(const float4*)(sW + k * 64 + tc * 8 + 4);
#pragma unroll
        for (int i = 0; i < 2; ++i) {
            float xk = sX[(tr + 32 * i) * 132 + k];
            acc[i][0] += xk * w0.x; acc[i][1] += xk * w0.y;
            acc[i][2] += xk * w0.z; acc[i][3] += xk * w0.w;
            acc[i][4] += xk * w1.x; acc[i][5] += xk * w1.y;
            acc[i][6] += xk * w1.z; acc[i][7] += xk * w1.w;
        }
    }
    float al[8], ar[8];
#pragma unroll
    for (int j = 0; j < 8; ++j) { al[j] = attn_l[tc * 8 + j]; ar[j] = attn_r[tc * 8 + j]; }
#pragma unroll
    for (int i = 0; i < 2; ++i) {
        int node = node0 + tr + 32 * i;
        float pl = 0.f, pr = 0.f;
#pragma unroll
        for (int j = 0; j < 8; ++j) { pl += acc[i][j] * al[j]; pr += acc[i][j] * ar[j]; }
        pl += __shfl_xor(pl, 1); pl += __shfl_xor(pl, 2); pl += __shfl_xor(pl, 4);
        pr += __shfl_xor(pr, 1); pr += __shfl_xor(pr, 2); pr += __shfl_xor(pr, 4);
        if (node < n) {
            float4 f0 = make_float4(acc[i][0], acc[i][1], acc[i][2], acc[i][3]);
            float4 f1 = make_float4(acc[i][4], acc[i][5], acc[i][6], acc[i][7]);
            *(float4*)(feat + (size_t)node * 64 + tc * 8) = f0;
            *(float4*)(feat + (size_t)node * 64 + tc * 8 + 4) = f1;
            if (tc == 0) { el[node] = pl; er[node] = pr; }
        }
    }
}

// ---------------- Layer 1 aggregation: wave per node, online softmax, fused bias+ELU ----------------
// lane l handles feat dims l (heads 0/1) and 64+l (heads 2/3)

__global__ __launch_bounds__(256) void k_edge_agg1(const int* __restrict__ row_start,
                                                   const int* __restrict__ csr_src,
                                                   const float* __restrict__ feat,
                                                   const float* __restrict__ el,
                                                   const float* __restrict__ er,
                                                   const float* __restrict__ bias,
                                                   float* __restrict__ xout, int n) {
    int wid = (blockIdx.x * blockDim.x + threadIdx.x) >> 6;
    int lane = threadIdx.x & 63;
    if (wid >= n) return;
    int h0 = lane >> 5;  // 0 or 1
    int h1 = h0 + 2;
    float er0 = er[wid * 4 + h0];
    float er1v = er[wid * 4 + h1];
    int start = row_start[wid], end = row_start[wid + 1];
    float m0 = -INFINITY, m1 = -INFINITY;
    float d0 = 0.f, d1 = 0.f, a0 = 0.f, a1 = 0.f;
    int s_next = (start < end) ? csr_src[start] : 0;
    for (int slot = start; slot < end; ++slot) {
        int s = s_next;
        if (slot + 1 < end) s_next = csr_src[slot + 1];
        float f0 = feat[(size_t)s * 128 + lane];
        float f1 = feat[(size_t)s * 128 + 64 + lane];
        float e0 = el[s * 4 + h0] + er0;
        float e1 = el[s * 4 + h1] + er1v;
        e0 = (e0 > 0.f) ? e0 : 0.2f * e0;
        e1 = (e1 > 0.f) ? e1 : 0.2f * e1;
        float nm0 = fmaxf(m0, e0);
        float nm1 = fmaxf(m1, e1);
        float sc0 = __expf(m0 - nm0);
        float sc1 = __expf(m1 - nm1);
        float w0 = __expf(e0 - nm0);
        float w1 = __expf(e1 - nm1);
        a0 = a0 * sc0 + w0 * f0; d0 = d0 * sc0 + w0; m0 = nm0;
        a1 = a1 * sc1 + w1 * f1; d1 = d1 * sc1 + w1; m1 = nm1;
    }
    float o0 = (end > start) ? a0 / d0 : 0.f;
    float o1 = (end > start) ? a1 / d1 : 0.f;
    o0 += bias[lane];
    o1 += bias[64 + lane];
    // ELU fused (between layers)
    o0 = (o0 > 0.f) ? o0 : (__expf(o0) - 1.f);
    o1 = (o1 > 0.f) ? o1 : (__expf(o1) - 1.f);
    xout[(size_t)wid * 128 + lane] = o0;
    xout[(size_t)wid * 128 + 64 + lane] = o1;
}

// ---------------- Layer 2 aggregation: wave per node, H=1, D=64 -> final output ----------------

__global__ __launch_bounds__(256) void k_edge_agg2(const int* __restrict__ row_start,
                                                   const int* __restrict__ csr_src,
                                                   const float* __restrict__ feat,
                                                   const float* __restrict__ el,
                                                   const float* __restrict__ er,
                                                   const float* __restrict__ bias,
                                                   float* __restrict__ out, int n) {
    int wid = (blockIdx.x * blockDim.x + threadIdx.x) >> 6;
    int lane = threadIdx.x & 63;
    if (wid >= n) return;
    float ern = er[wid];
    int start = row_start[wid], end = row_start[wid + 1];
    float m = -INFINITY, d = 0.f, a = 0.f;
    int s_next = (start < end) ? csr_src[start] : 0;
    for (int slot = start; slot < end; ++slot) {
        int s = s_next;
        if (slot + 1 < end) s_next = csr_src[slot + 1];
        float f = feat[(size_t)s * 64 + lane];
        float e = el[s] + ern;
        e = (e > 0.f) ? e : 0.2f * e;
        float nm = fmaxf(m, e);
        float sc = __expf(m - nm);
        float w = __expf(e - nm);
        a = a * sc + w * f; d = d * sc + w; m = nm;
    }
    float o = (end > start) ? a / d : 0.f;
    out[(size_t)wid * 64 + lane] = o + bias[lane];
}

// ---------------- launch ----------------

extern "C" void kernel_launch(void* const* d_in, const int* in_sizes, int n_in,
                              void* d_out, int out_size, void* d_ws, size_t ws_size,
                              hipStream_t stream) {
    const float* features = (const float*)d_in[0];
    const int* src = (const int*)d_in[1];
    const int* dst = (const int*)d_in[2];
    const float* fc1_w = (const float*)d_in[3];
    const float* attn_l1 = (const float*)d_in[4];
    const float* attn_r1 = (const float*)d_in[5];
    const float* bias1 = (const float*)d_in[6];
    const float* fc2_w = (const float*)d_in[7];
    const float* attn_l2 = (const float*)d_in[8];
    const float* attn_r2 = (const float*)d_in[9];
    const float* bias2 = (const float*)d_in[10];
    const int N = in_sizes[0] / 128;
    const int E = in_sizes[1];

    char* ws = (char*)d_ws;
    size_t off = 0;
    auto alloc = [&](size_t bytes) {
        void* p = ws + off;
        off = (off + bytes + 255) & ~(size_t)255;
        return p;
    };
    int* cnt = (int*)alloc((size_t)N * 4);
    int* fill = (int*)alloc((size_t)N * 4);
    int* row_start = (int*)alloc((size_t)(N + 1) * 4);
    int* partials = (int*)alloc(1024 * 4);
    int* csr_src = (int*)alloc((size_t)E * 4);
    float* feat1 = (float*)alloc((size_t)N * 128 * 4);
    float* el1 = (float*)alloc((size_t)N * 4 * 4);
    float* er1 = (float*)alloc((size_t)N * 4 * 4);
    float* x2 = (float*)alloc((size_t)N * 128 * 4);
    float* feat2 = (float*)alloc((size_t)N * 64 * 4);
    float* el2 = (float*)alloc((size_t)N * 4);
    float* er2 = (float*)alloc((size_t)N * 4);

    hipMemsetAsync(cnt, 0, (size_t)N * 4, stream);
    hipMemsetAsync(fill, 0, (size_t)N * 4, stream);

    k_count<<<(E + 255) / 256, 256, 0, stream>>>(dst, cnt, E);
    int nb = (N + 1023) / 1024;
    k_scan_local<<<nb, 256, 0, stream>>>(cnt, row_start, partials, N);
    k_scan_partials<<<1, 256, 0, stream>>>(partials, nb);
    k_scan_add<<<(N + 255) / 256, 256, 0, stream>>>(row_start, partials, N, E);
    k_scatter<<<(E + 255) / 256, 256, 0, stream>>>(src, dst, row_start, fill, csr_src, E);

    k_gemm1<<<(N + 63) / 64, 256, 0, stream>>>(features, fc1_w, attn_l1, attn_r1, feat1, el1, er1, N);
    k_edge_agg1<<<(N + 3) / 4, 256, 0, stream>>>(row_start, csr_src, feat1, el1, er1, bias1, x2, N);
    k_gemm2<<<(N + 63) / 64, 256, 0, stream>>>(x2, fc2_w, attn_l2, attn_r2, feat2, el2, er2, N);
    k_edge_agg2<<<(N + 3) / 4, 256, 0, stream>>>(row_start, csr_src, feat2, el2, er2, bias2, (float*)d_out, N);
}